// Round 2
// baseline (204.971 us; speedup 1.0000x reference)
//
#include <hip/hip_runtime.h>
#include <hip/hip_bf16.h>

typedef __bf16 bf16x8 __attribute__((ext_vector_type(8)));
typedef float floatx4 __attribute__((ext_vector_type(4)));

__device__ __forceinline__ unsigned short f2bf(float f) {
  __bf16 b = (__bf16)f;
  return __builtin_bit_cast(unsigned short, b);
}

// ---------------------------------------------------------------------------
// Kernel 1: decode w1 bits -> bf16 {-1,0,+1} matrix [256][800] (K padded
// 784->800 with zeros). One thread per 8-weight group.
// ---------------------------------------------------------------------------
__global__ void decode_w1_kernel(const int* __restrict__ w1p,
                                 const int* __restrict__ m1p,
                                 unsigned short* __restrict__ w1d) {
  int t = blockIdx.x * 256 + threadIdx.x;
  if (t >= 256 * 100) return;
  int r = t / 100;
  int j = t - r * 100;
  unsigned short vals[8];
#pragma unroll
  for (int k = 0; k < 8; ++k) vals[k] = 0;
  if (j < 98) {
    unsigned int v = (unsigned int)w1p[r * 98 + j];
    unsigned int m = (unsigned int)m1p[r * 98 + j];
#pragma unroll
    for (int k = 0; k < 8; ++k) {           // MSB-first per byte (matches _unpack)
      unsigned int bit = (v >> (7 - k)) & 1u;
      unsigned int mk  = (m >> (7 - k)) & 1u;
      vals[k] = (unsigned short)(mk ? (bit ? 0x3F80u : 0xBF80u) : 0u);
    }
  }
  uint4 pack;
  pack.x = (unsigned)vals[0] | ((unsigned)vals[1] << 16);
  pack.y = (unsigned)vals[2] | ((unsigned)vals[3] << 16);
  pack.z = (unsigned)vals[4] | ((unsigned)vals[5] << 16);
  pack.w = (unsigned)vals[6] | ((unsigned)vals[7] << 16);
  *reinterpret_cast<uint4*>(w1d + t * 8) = pack;  // r*800 + j*8 == 8*t
}

// ---------------------------------------------------------------------------
// Kernel 2: fused  h = relu(a1 * x@W1^T);  out = a2 * (h@W2^T)
// BARRIER-FREE main loop: A (x, fp32->bf16 in regs) and B (w1d, one 16B load
// per frag) come straight from global; no LDS, no __syncthreads in the K-loop,
// so loads stay in flight across chunks (no vmcnt(0) drain).
// 512 blocks x 256 threads. Block = 64 rows x 256 h-cols.
// Wave split 2m x 2n: wave (wm,wn) owns rows wm*32..+32, cols wn*128..+128.
// mfma_f32_16x16x32_bf16: A[m=l15][k=quad*8+j], B^T[n=l15][k=quad*8+j],
// C/D col=l15, row=quad*4+reg (m89-verified).
// ---------------------------------------------------------------------------
#define W1LD 800
#define HS_LD 264   // 256 + 8 pad for layer-2 reads

__global__ __launch_bounds__(256, 2) void fused_kernel(
    const float* __restrict__ x,
    const unsigned short* __restrict__ w1d,
    const int* __restrict__ w2p,
    const int* __restrict__ m2p,
    const float* __restrict__ a1p,
    const float* __restrict__ a2p,
    float* __restrict__ out) {
  // LDS only for the epilogue: Hs[64][264] @ 0, W2s[16][256] @ 16896 (shorts)
  __shared__ unsigned short smem[64 * HS_LD + 16 * 256];  // 41984 B

  const int tid  = threadIdx.x;
  const int wave = tid >> 6;
  const int lane = tid & 63;
  const int l15  = lane & 15;
  const int quad = lane >> 4;
  const int wm   = wave >> 1;   // 0..1  m-half
  const int wn   = wave & 1;    // 0..1  n-half
  const int row0 = blockIdx.x * 64;

  const int OFF_HS = 0;
  const int OFF_W2 = 64 * HS_LD;

  // per-lane base pointers
  const float* xbase[2];
#pragma unroll
  for (int mi = 0; mi < 2; ++mi)
    xbase[mi] = x + (size_t)(row0 + wm * 32 + mi * 16 + l15) * 784;
  const unsigned short* wbase[8];
#pragma unroll
  for (int nj = 0; nj < 8; ++nj)
    wbase[nj] = w1d + (size_t)(wn * 128 + nj * 16 + l15) * W1LD;

  floatx4 acc[2][8];
#pragma unroll
  for (int i = 0; i < 2; ++i)
#pragma unroll
    for (int j = 0; j < 8; ++j) acc[i][j] = (floatx4){0.f, 0.f, 0.f, 0.f};

  const float4 z4 = (float4){0.f, 0.f, 0.f, 0.f};

  // A-chunk loader: 2 m-tiles x 8 fp32 (2x float4). k >= 784 -> zeros (pad).
  auto ldA = [&](int kc, float4 a[2][2]) {
    int k = kc * 32 + quad * 8;
    bool ok = (k < 784);
#pragma unroll
    for (int mi = 0; mi < 2; ++mi) {
      if (ok) {
        a[mi][0] = *reinterpret_cast<const float4*>(xbase[mi] + k);
        a[mi][1] = *reinterpret_cast<const float4*>(xbase[mi] + k + 4);
      } else {
        a[mi][0] = z4;
        a[mi][1] = z4;
      }
    }
  };

  float4 cur[2][2], nxt[2][2];
  ldA(0, cur);

#pragma unroll 1
  for (int kc = 0; kc < 25; ++kc) {
    // B frags for this chunk (L2-resident w1d, one dwordx4 each)
    int kb = kc * 32 + quad * 8;
    bf16x8 bfrag[8];
#pragma unroll
    for (int nj = 0; nj < 8; ++nj)
      bfrag[nj] = *reinterpret_cast<const bf16x8*>(wbase[nj] + kb);
    // prefetch next A chunk (HBM latency hidden behind this chunk's MFMAs)
    if (kc < 24) ldA(kc + 1, nxt);
    // convert current A fp32 -> bf16 frags
    bf16x8 afrag[2];
#pragma unroll
    for (int mi = 0; mi < 2; ++mi) {
      afrag[mi][0] = (__bf16)cur[mi][0].x;
      afrag[mi][1] = (__bf16)cur[mi][0].y;
      afrag[mi][2] = (__bf16)cur[mi][0].z;
      afrag[mi][3] = (__bf16)cur[mi][0].w;
      afrag[mi][4] = (__bf16)cur[mi][1].x;
      afrag[mi][5] = (__bf16)cur[mi][1].y;
      afrag[mi][6] = (__bf16)cur[mi][1].z;
      afrag[mi][7] = (__bf16)cur[mi][1].w;
    }
#pragma unroll
    for (int mi = 0; mi < 2; ++mi)
#pragma unroll
      for (int nj = 0; nj < 8; ++nj)
        acc[mi][nj] = __builtin_amdgcn_mfma_f32_16x16x32_bf16(
            afrag[mi], bfrag[nj], acc[mi][nj], 0, 0, 0);
#pragma unroll
    for (int mi = 0; mi < 2; ++mi) {
      cur[mi][0] = nxt[mi][0];
      cur[mi][1] = nxt[mi][1];
    }
  }

  // ---- epilogue layer 1: h = relu(a1*acc) -> Hs bf16 ----
  const float a1 = a1p[0];
  const float a2 = a2p[0];
#pragma unroll
  for (int mi = 0; mi < 2; ++mi) {
#pragma unroll
    for (int nj = 0; nj < 8; ++nj) {
      int col   = wn * 128 + nj * 16 + l15;
      int rbase = wm * 32 + mi * 16 + quad * 4;
#pragma unroll
      for (int r = 0; r < 4; ++r) {
        float h = fmaxf(a1 * acc[mi][nj][r], 0.f);
        smem[OFF_HS + (rbase + r) * HS_LD + col] = f2bf(h);
      }
    }
  }
  // ---- decode w2 -> W2s[16][256] (rows 10..15 zero) ----
#pragma unroll
  for (int it = 0; it < 2; ++it) {
    int idx = it * 256 + tid;
    if (idx < 320) {
      int r = idx >> 5, j = idx & 31;
      unsigned int v = (unsigned int)w2p[r * 32 + j];
      unsigned int m = (unsigned int)m2p[r * 32 + j];
#pragma unroll
      for (int k = 0; k < 8; ++k) {
        unsigned int bit = (v >> (7 - k)) & 1u;
        unsigned int mk  = (m >> (7 - k)) & 1u;
        smem[OFF_W2 + r * 256 + j * 8 + k] =
            (unsigned short)(mk ? (bit ? 0x3F80u : 0xBF80u) : 0u);
      }
    }
  }
#pragma unroll
  for (int r = 10; r < 16; ++r) smem[OFF_W2 + r * 256 + tid] = 0;
  __syncthreads();

  // ---- layer 2: out[64][10] = Hs @ W2s^T; wave handles 16 rows, K=256 ----
  floatx4 o2 = (floatx4){0.f, 0.f, 0.f, 0.f};
#pragma unroll
  for (int ks = 0; ks < 8; ++ks) {
    bf16x8 ha = *reinterpret_cast<const bf16x8*>(
        &smem[OFF_HS + (wave * 16 + l15) * HS_LD + ks * 32 + quad * 8]);
    bf16x8 wb = *reinterpret_cast<const bf16x8*>(
        &smem[OFF_W2 + l15 * 256 + ks * 32 + quad * 8]);
    o2 = __builtin_amdgcn_mfma_f32_16x16x32_bf16(ha, wb, o2, 0, 0, 0);
  }
  if (l15 < 10) {
#pragma unroll
    for (int r = 0; r < 4; ++r) {
      int gr = row0 + wave * 16 + quad * 4 + r;
      out[(size_t)gr * 10 + l15] = a2 * o2[r];
    }
  }
}

extern "C" void kernel_launch(void* const* d_in, const int* in_sizes, int n_in,
                              void* d_out, int out_size, void* d_ws, size_t ws_size,
                              hipStream_t stream) {
  const float* x   = (const float*)d_in[0];
  const int*   w1p = (const int*)d_in[1];
  const int*   m1p = (const int*)d_in[2];
  const float* a1  = (const float*)d_in[3];
  const int*   w2p = (const int*)d_in[4];
  const int*   m2p = (const int*)d_in[5];
  const float* a2  = (const float*)d_in[6];
  unsigned short* w1d = (unsigned short*)d_ws;  // 256*800 bf16 = 400 KB scratch
  float* out = (float*)d_out;

  decode_w1_kernel<<<100, 256, 0, stream>>>(w1p, m1p, w1d);
  fused_kernel<<<512, 256, 0, stream>>>(x, w1d, w2p, m2p, a1, a2, out);
}

// Round 4
// 191.539 us; speedup vs baseline: 1.0701x; 1.0701x over previous
//
#include <hip/hip_runtime.h>
#include <hip/hip_bf16.h>

typedef __bf16 bf16x8 __attribute__((ext_vector_type(8)));
typedef float floatx4 __attribute__((ext_vector_type(4)));

__device__ __forceinline__ unsigned short f2bf(float f) {
  __bf16 b = (__bf16)f;
  return __builtin_bit_cast(unsigned short, b);
}

// ---------------------------------------------------------------------------
// Kernel 1: decode w1 bits -> bf16 {-1,0,+1} in a SWIZZLED fragment-major
// layout (K padded 784->800 with zeros):
//   off(row r, col c) = ((r>>4)*25 + (c>>5))*512 + (r&15)*32 + (c&31)
// i.e. for each (16-row tile, 32-col K-chunk) the 16x32 fragment block is one
// contiguous 1KB run -> the GEMM's B-loads are perfectly coalesced.
// One thread per 8-weight group.
// ---------------------------------------------------------------------------
__global__ void decode_w1_kernel(const int* __restrict__ w1p,
                                 const int* __restrict__ m1p,
                                 unsigned short* __restrict__ w1d) {
  int t = blockIdx.x * 256 + threadIdx.x;
  if (t >= 256 * 100) return;
  int r = t / 100;
  int j = t - r * 100;
  unsigned short vals[8];
#pragma unroll
  for (int k = 0; k < 8; ++k) vals[k] = 0;
  if (j < 98) {
    unsigned int v = (unsigned int)w1p[r * 98 + j];
    unsigned int m = (unsigned int)m1p[r * 98 + j];
#pragma unroll
    for (int k = 0; k < 8; ++k) {           // MSB-first per byte (matches _unpack)
      unsigned int bit = (v >> (7 - k)) & 1u;
      unsigned int mk  = (m >> (7 - k)) & 1u;
      vals[k] = (unsigned short)(mk ? (bit ? 0x3F80u : 0xBF80u) : 0u);
    }
  }
  uint4 pack;
  pack.x = (unsigned)vals[0] | ((unsigned)vals[1] << 16);
  pack.y = (unsigned)vals[2] | ((unsigned)vals[3] << 16);
  pack.z = (unsigned)vals[4] | ((unsigned)vals[5] << 16);
  pack.w = (unsigned)vals[6] | ((unsigned)vals[7] << 16);
  int c0   = j * 8;                          // 16B-aligned (c0&31 in {0,8,16,24})
  int off  = (((r >> 4) * 25 + (c0 >> 5)) << 9) + ((r & 15) << 5) + (c0 & 31);
  *reinterpret_cast<uint4*>(w1d + off) = pack;
}

// ---------------------------------------------------------------------------
// Kernel 2: fused  h = relu(a1 * x@W1^T);  out = a2 * (h@W2^T)
// BM=32: block's 32 x-rows = ONE contiguous 100KB stream, staged fp32->bf16
// into LDS slab [32][808] once. K-loop (25 chunks) is BARRIER-FREE:
//   A: ds_read_b128 from slab (row stride 1616B -> 2-way bank alias, free)
//   B: coalesced 1KB wave-loads from swizzled L2-resident w1d, clamped
//      distance-1 register prefetch (no undef values).
// 1024 blocks x 256 threads (4 waves); wave owns cols wave*64..+63
// (4 n-tiles) x 32 rows (2 m-tiles) -> 8 MFMAs/chunk.
// mfma_f32_16x16x32_bf16: A[m=l15][k=quad*8+j], B^T[n=l15][k=quad*8+j],
// C/D col=l15, row=quad*4+reg (m89-verified).
// ---------------------------------------------------------------------------
#define W1TILE 12800  // shorts per 16-row swizzled tile: 25 chunks * 512
#define SLAB_LD 808   // shorts; rows 16B-aligned (1616B); dword stride 404
#define HS_LD 264
#define OFF_W2 (32 * HS_LD)   // W2s[16][264] after Hs[32][264] (overlay on slab)

__global__ __launch_bounds__(256, 3) void fused_kernel(
    const float* __restrict__ x,
    const unsigned short* __restrict__ w1d,
    const int* __restrict__ w2p,
    const int* __restrict__ m2p,
    const float* __restrict__ a1p,
    const float* __restrict__ a2p,
    float* __restrict__ out) {
  // phase 1: x slab [32][808] bf16 = 51712 B.
  // phase 2 (overlay): Hs[32][264] + W2s[16][264] = 25344 B.
  __shared__ unsigned short smem[32 * SLAB_LD];

  const int tid  = threadIdx.x;
  const int wave = tid >> 6;    // 0..3
  const int lane = tid & 63;
  const int l15  = lane & 15;
  const int quad = lane >> 4;
  const int row0 = blockIdx.x * 32;

  // ---- phase 0: stage x slab (contiguous 100352B stream), cvt -> bf16 ----
  const float* xs = x + (size_t)row0 * 784;
#pragma unroll
  for (int i = 0; i < 25; ++i) {
    int f = i * 256 + tid;               // float4 index, 6272 total
    if (f < 6272) {
      float4 v = *reinterpret_cast<const float4*>(xs + (size_t)f * 4);
      int r = f / 196;                   // 196 float4s per 784-fp32 row
      int c = (f - r * 196) * 4;
      ushort4 b;
      b.x = f2bf(v.x); b.y = f2bf(v.y); b.z = f2bf(v.z); b.w = f2bf(v.w);
      *reinterpret_cast<ushort4*>(&smem[r * SLAB_LD + c]) = b;
    }
  }
  if (tid < 128) {                       // zero K-pad cols 784..799
    int r = tid >> 2, g = tid & 3;
    ushort4 z = {0, 0, 0, 0};
    *reinterpret_cast<ushort4*>(&smem[r * SLAB_LD + 784 + g * 4]) = z;
  }
  __syncthreads();

  // ---- K-loop: 25 chunks, barrier-free ----
  // B base for n-tile nj: swizzled tile T = wave*4+nj; per-lane offset
  // l15*32 + quad*8 shorts -> the wave's 64 lanes cover one contiguous 1KB run.
  const unsigned short* wb[4];
#pragma unroll
  for (int nj = 0; nj < 4; ++nj)
    wb[nj] = w1d + (size_t)(wave * 4 + nj) * W1TILE + l15 * 32 + quad * 8;

  floatx4 acc[2][4];
#pragma unroll
  for (int i = 0; i < 2; ++i)
#pragma unroll
    for (int j = 0; j < 4; ++j) acc[i][j] = (floatx4){0.f, 0.f, 0.f, 0.f};

  bf16x8 bcur[4], bnext[4];
#pragma unroll
  for (int nj = 0; nj < 4; ++nj)
    bcur[nj] = *reinterpret_cast<const bf16x8*>(wb[nj]);

#pragma unroll 1
  for (int kc = 0; kc < 25; ++kc) {
    int kn = (kc < 24) ? (kc + 1) : 24;  // clamped: always in-bounds, no undef
#pragma unroll
    for (int nj = 0; nj < 4; ++nj)
      bnext[nj] = *reinterpret_cast<const bf16x8*>(wb[nj] + kn * 512);
    const int ko = kc * 32 + quad * 8;
    bf16x8 a0 = *reinterpret_cast<const bf16x8*>(&smem[l15 * SLAB_LD + ko]);
    bf16x8 a1 =
        *reinterpret_cast<const bf16x8*>(&smem[(16 + l15) * SLAB_LD + ko]);
#pragma unroll
    for (int nj = 0; nj < 4; ++nj) {
      acc[0][nj] = __builtin_amdgcn_mfma_f32_16x16x32_bf16(a0, bcur[nj],
                                                           acc[0][nj], 0, 0, 0);
      acc[1][nj] = __builtin_amdgcn_mfma_f32_16x16x32_bf16(a1, bcur[nj],
                                                           acc[1][nj], 0, 0, 0);
    }
#pragma unroll
    for (int nj = 0; nj < 4; ++nj) bcur[nj] = bnext[nj];
  }

  __syncthreads();   // all slab reads done before Hs overlays it

  // ---- epilogue layer 1: h = relu(a1*acc) -> Hs[32][264] bf16 ----
  const float a1s = a1p[0];
  const float a2s = a2p[0];
#pragma unroll
  for (int mi = 0; mi < 2; ++mi) {
#pragma unroll
    for (int nj = 0; nj < 4; ++nj) {
      int col   = wave * 64 + nj * 16 + l15;
      int rbase = mi * 16 + quad * 4;
#pragma unroll
      for (int r = 0; r < 4; ++r) {
        float h = fmaxf(a1s * acc[mi][nj][r], 0.f);
        smem[(rbase + r) * HS_LD + col] = f2bf(h);
      }
    }
  }
  // ---- decode w2 -> W2s[16][264] (rows 10..15 zero) ----
#pragma unroll
  for (int it = 0; it < 2; ++it) {
    int idx = it * 256 + tid;
    if (idx < 320) {
      int r = idx >> 5, j = idx & 31;
      unsigned int v = (unsigned int)w2p[r * 32 + j];
      unsigned int m = (unsigned int)m2p[r * 32 + j];
#pragma unroll
      for (int k = 0; k < 8; ++k) {
        unsigned int bit = (v >> (7 - k)) & 1u;
        unsigned int mk  = (m >> (7 - k)) & 1u;
        smem[OFF_W2 + r * HS_LD + j * 8 + k] =
            (unsigned short)(mk ? (bit ? 0x3F80u : 0xBF80u) : 0u);
      }
    }
  }
#pragma unroll
  for (int r = 10; r < 16; ++r) smem[OFF_W2 + r * HS_LD + tid] = 0;
  __syncthreads();

  // ---- layer 2: out[32][10] = Hs @ W2s^T; waves 0-1, 16 rows each, K=256 ---
  if (wave < 2) {
    floatx4 o2 = (floatx4){0.f, 0.f, 0.f, 0.f};
#pragma unroll
    for (int ks = 0; ks < 8; ++ks) {
      bf16x8 ha = *reinterpret_cast<const bf16x8*>(
          &smem[(wave * 16 + l15) * HS_LD + ks * 32 + quad * 8]);
      bf16x8 wv = *reinterpret_cast<const bf16x8*>(
          &smem[OFF_W2 + l15 * HS_LD + ks * 32 + quad * 8]);
      o2 = __builtin_amdgcn_mfma_f32_16x16x32_bf16(ha, wv, o2, 0, 0, 0);
    }
    if (l15 < 10) {
#pragma unroll
      for (int r = 0; r < 4; ++r) {
        int gr = row0 + wave * 16 + quad * 4 + r;
        out[(size_t)gr * 10 + l15] = a2s * o2[r];
      }
    }
  }
}

extern "C" void kernel_launch(void* const* d_in, const int* in_sizes, int n_in,
                              void* d_out, int out_size, void* d_ws, size_t ws_size,
                              hipStream_t stream) {
  const float* x   = (const float*)d_in[0];
  const int*   w1p = (const int*)d_in[1];
  const int*   m1p = (const int*)d_in[2];
  const float* a1  = (const float*)d_in[3];
  const int*   w2p = (const int*)d_in[4];
  const int*   m2p = (const int*)d_in[5];
  const float* a2  = (const float*)d_in[6];
  unsigned short* w1d = (unsigned short*)d_ws;  // 256*800 bf16 = 400 KB scratch
  float* out = (float*)d_out;

  decode_w1_kernel<<<100, 256, 0, stream>>>(w1p, m1p, w1d);
  fused_kernel<<<1024, 256, 0, stream>>>(x, w1d, w2p, m2p, a1, a2, out);
}